// Round 1
// baseline (6866.283 us; speedup 1.0000x reference)
//
#include <hip/hip_runtime.h>
#include <hip/hip_bf16.h>
#include <math.h>

typedef unsigned short ushort;
typedef __attribute__((ext_vector_type(8))) short short8;
typedef __attribute__((ext_vector_type(4))) float f4v;

constexpr int SEQ = 2048;
constexpr int DM  = 768;
constexpr int NH  = 12;
constexpr int HDM = 64;
constexpr int FF  = 3072;
constexpr int NL  = 12;
constexpr int NV  = 50257;

__device__ inline ushort f2bf(float f) {
    union { float f; unsigned u; } v; v.f = f;
    unsigned r = v.u + 0x7fffu + ((v.u >> 16) & 1u);
    return (ushort)(r >> 16);
}

// ---------------- LayerNorm: fp32 in -> bf16 out ----------------
__global__ __launch_bounds__(256) void ln_kernel(const float* __restrict__ x,
                                                 const float* __restrict__ g,
                                                 const float* __restrict__ b,
                                                 ushort* __restrict__ out) {
    int row = blockIdx.x;
    int t = threadIdx.x;
    const float* xr = x + (size_t)row * DM;
    float v0 = xr[t], v1 = xr[t + 256], v2 = xr[t + 512];
    float s = v0 + v1 + v2;
    float s2 = v0 * v0 + v1 * v1 + v2 * v2;
    for (int m = 1; m < 64; m <<= 1) { s += __shfl_xor(s, m); s2 += __shfl_xor(s2, m); }
    __shared__ float ls[4], ls2[4];
    int w = t >> 6;
    if ((t & 63) == 0) { ls[w] = s; ls2[w] = s2; }
    __syncthreads();
    s = ls[0] + ls[1] + ls[2] + ls[3];
    s2 = ls2[0] + ls2[1] + ls2[2] + ls2[3];
    float mu = s * (1.0f / DM);
    float var = s2 * (1.0f / DM) - mu * mu;
    float rs = rsqrtf(var + 1e-5f);
    ushort* o = out + (size_t)row * DM;
    o[t]       = f2bf((v0 - mu) * rs * g[t]       + b[t]);
    o[t + 256] = f2bf((v1 - mu) * rs * g[t + 256] + b[t + 256]);
    o[t + 512] = f2bf((v2 - mu) * rs * g[t + 512] + b[t + 512]);
}

// ---------------- GEMM: C[M,N] = A_bf16[M,K] @ B_f32[K,N] (+epilogue) ------
// EPI 0: store bf16
// EPI 1: fp32 out = acc + bias[col] + res[row,col]
// EPI 2: bf16 out = gelu(acc + bias[col])
// EPI 3: fp32 out = acc, N-bounds guarded (LM head, scalar B loads)
template <int EPI>
__global__ __launch_bounds__(256) void gemm64(const ushort* __restrict__ A,
                                              const float* __restrict__ B,
                                              const float* __restrict__ bias,
                                              const float* __restrict__ res,
                                              void* __restrict__ outp,
                                              int M, int N, int K) {
    __shared__ ushort As[64][64];   // [m][k]
    __shared__ ushort Bs[64][72];   // [n][k] (transposed, padded)
    int tid = threadIdx.x;
    int lane = tid & 63, wave = tid >> 6;
    int wm = (wave >> 1) * 32, wn = (wave & 1) * 32;
    int mBase = blockIdx.x * 64, nBase = blockIdx.y * 64;
    int lr = lane & 15, lg = lane >> 4;

    const f4v fz = {0.f, 0.f, 0.f, 0.f};
    f4v acc[2][2];
    acc[0][0] = fz; acc[0][1] = fz; acc[1][0] = fz; acc[1][1] = fz;

    int ar = tid >> 2, ac = (tid & 3) * 16;   // A stage: row ar, cols ac..ac+15
    int br = tid >> 2, bc = (tid & 3) * 16;   // B stage: k-row br, n-cols bc..bc+15

    for (int kb = 0; kb < K; kb += 64) {
        const short8* ag = (const short8*)(A + (size_t)(mBase + ar) * K + kb + ac);
        *(short8*)&As[ar][ac]     = ag[0];
        *(short8*)&As[ar][ac + 8] = ag[1];
        if constexpr (EPI == 3) {
            #pragma unroll
            for (int j = 0; j < 16; ++j) {
                int col = nBase + bc + j;
                float f = (col < N) ? B[(size_t)(kb + br) * N + col] : 0.f;
                Bs[bc + j][br] = f2bf(f);
            }
        } else {
            const float4* bg = (const float4*)(B + (size_t)(kb + br) * N + nBase + bc);
            float fv[16];
            *(float4*)&fv[0]  = bg[0];
            *(float4*)&fv[4]  = bg[1];
            *(float4*)&fv[8]  = bg[2];
            *(float4*)&fv[12] = bg[3];
            #pragma unroll
            for (int j = 0; j < 16; ++j) Bs[bc + j][br] = f2bf(fv[j]);
        }
        __syncthreads();
        #pragma unroll
        for (int kk = 0; kk < 2; ++kk) {
            short8 a0 = *(const short8*)&As[wm + lr][kk * 32 + lg * 8];
            short8 a1 = *(const short8*)&As[wm + 16 + lr][kk * 32 + lg * 8];
            short8 b0 = *(const short8*)&Bs[wn + lr][kk * 32 + lg * 8];
            short8 b1 = *(const short8*)&Bs[wn + 16 + lr][kk * 32 + lg * 8];
            acc[0][0] = __builtin_amdgcn_mfma_f32_16x16x32_bf16(a0, b0, acc[0][0], 0, 0, 0);
            acc[0][1] = __builtin_amdgcn_mfma_f32_16x16x32_bf16(a0, b1, acc[0][1], 0, 0, 0);
            acc[1][0] = __builtin_amdgcn_mfma_f32_16x16x32_bf16(a1, b0, acc[1][0], 0, 0, 0);
            acc[1][1] = __builtin_amdgcn_mfma_f32_16x16x32_bf16(a1, b1, acc[1][1], 0, 0, 0);
        }
        __syncthreads();
    }

    #pragma unroll
    for (int fm = 0; fm < 2; ++fm)
        #pragma unroll
        for (int fn = 0; fn < 2; ++fn)
            #pragma unroll
            for (int r = 0; r < 4; ++r) {
                int row = mBase + wm + fm * 16 + 4 * lg + r;
                int col = nBase + wn + fn * 16 + lr;
                float v = acc[fm][fn][r];
                if constexpr (EPI == 0) {
                    ((ushort*)outp)[(size_t)row * N + col] = f2bf(v);
                } else if constexpr (EPI == 1) {
                    v += bias[col] + res[(size_t)row * N + col];
                    ((float*)outp)[(size_t)row * N + col] = v;
                } else if constexpr (EPI == 2) {
                    v += bias[col];
                    v = 0.5f * v * (1.f + erff(v * 0.70710678118f));
                    ((ushort*)outp)[(size_t)row * N + col] = f2bf(v);
                } else {
                    if (col < N) ((float*)outp)[(size_t)row * N + col] = v;
                }
            }
}

// ---------------- Flash attention (causal, no 1/sqrt(d) scale) -------------
// grid: (SEQ/64, NH). block: 256 = 4 waves, each wave owns 16 q-rows.
__global__ __launch_bounds__(256) void attn_kernel(const ushort* __restrict__ Qg,
                                                   const ushort* __restrict__ Kg,
                                                   const ushort* __restrict__ Vg,
                                                   ushort* __restrict__ Og) {
    __shared__ ushort Ks[64][64];       // [k_local][d]
    __shared__ ushort Vs[64][72];       // [d][k_local] transposed, padded
    __shared__ ushort Ps[4][16][64];    // per-wave P tile
    int tid = threadIdx.x, lane = tid & 63, wave = tid >> 6;
    int qb = blockIdx.x, head = blockIdx.y;
    int lr = lane & 15, lg = lane >> 4;
    int qr0 = qb * 64 + wave * 16;
    size_t hoff = (size_t)head * HDM;

    short8 qf0 = *(const short8*)(Qg + (size_t)(qr0 + lr) * DM + hoff + lg * 8);
    short8 qf1 = *(const short8*)(Qg + (size_t)(qr0 + lr) * DM + hoff + 32 + lg * 8);

    const f4v fz = {0.f, 0.f, 0.f, 0.f};
    f4v o[4];
    o[0] = fz; o[1] = fz; o[2] = fz; o[3] = fz;
    float mrow[4] = {-1e30f, -1e30f, -1e30f, -1e30f};
    float lsum[4] = {0.f, 0.f, 0.f, 0.f};

    int r_ = tid >> 2, c_ = (tid & 3) * 16;

    for (int kb = 0; kb <= qb; ++kb) {
        // cooperative stage of K (row-major) and V (transposed)
        const short8* kg = (const short8*)(Kg + (size_t)(kb * 64 + r_) * DM + hoff + c_);
        *(short8*)&Ks[r_][c_]     = kg[0];
        *(short8*)&Ks[r_][c_ + 8] = kg[1];
        const short8* vg = (const short8*)(Vg + (size_t)(kb * 64 + r_) * DM + hoff + c_);
        short8 v0 = vg[0], v1 = vg[1];
        #pragma unroll
        for (int j = 0; j < 8; ++j) {
            Vs[c_ + j][r_]     = (ushort)v0[j];
            Vs[c_ + 8 + j][r_] = (ushort)v1[j];
        }
        __syncthreads();

        // S = Q K^T  (16 q-rows x 64 k-cols per wave)
        f4v s[4];
        #pragma unroll
        for (int n = 0; n < 4; ++n) {
            short8 k0 = *(const short8*)&Ks[n * 16 + lr][lg * 8];
            short8 k1 = *(const short8*)&Ks[n * 16 + lr][32 + lg * 8];
            f4v z = fz;
            z = __builtin_amdgcn_mfma_f32_16x16x32_bf16(qf0, k0, z, 0, 0, 0);
            s[n] = __builtin_amdgcn_mfma_f32_16x16x32_bf16(qf1, k1, z, 0, 0, 0);
        }
        if (kb == qb) {
            #pragma unroll
            for (int n = 0; n < 4; ++n)
                #pragma unroll
                for (int r = 0; r < 4; ++r) {
                    int col = kb * 64 + n * 16 + lr;
                    int row = qr0 + 4 * lg + r;
                    if (col > row) s[n][r] = -1e38f;
                }
        }

        // online softmax, P -> LDS (bf16)
        #pragma unroll
        for (int r = 0; r < 4; ++r) {
            float mx = fmaxf(fmaxf(s[0][r], s[1][r]), fmaxf(s[2][r], s[3][r]));
            mx = fmaxf(mx, __shfl_xor(mx, 1));
            mx = fmaxf(mx, __shfl_xor(mx, 2));
            mx = fmaxf(mx, __shfl_xor(mx, 4));
            mx = fmaxf(mx, __shfl_xor(mx, 8));
            float mnew = fmaxf(mrow[r], mx);
            float corr = expf(mrow[r] - mnew);
            float ps0 = expf(s[0][r] - mnew);
            float ps1 = expf(s[1][r] - mnew);
            float ps2 = expf(s[2][r] - mnew);
            float ps3 = expf(s[3][r] - mnew);
            float rs = ps0 + ps1 + ps2 + ps3;
            rs += __shfl_xor(rs, 1);
            rs += __shfl_xor(rs, 2);
            rs += __shfl_xor(rs, 4);
            rs += __shfl_xor(rs, 8);
            lsum[r] = lsum[r] * corr + rs;
            mrow[r] = mnew;
            o[0][r] *= corr; o[1][r] *= corr; o[2][r] *= corr; o[3][r] *= corr;
            Ps[wave][4 * lg + r][0 * 16 + lr] = f2bf(ps0);
            Ps[wave][4 * lg + r][1 * 16 + lr] = f2bf(ps1);
            Ps[wave][4 * lg + r][2 * 16 + lr] = f2bf(ps2);
            Ps[wave][4 * lg + r][3 * 16 + lr] = f2bf(ps3);
        }
        __syncthreads();

        // O += P V
        #pragma unroll
        for (int kk = 0; kk < 2; ++kk) {
            short8 pa = *(const short8*)&Ps[wave][lr][kk * 32 + lg * 8];
            #pragma unroll
            for (int dn = 0; dn < 4; ++dn) {
                short8 vb = *(const short8*)&Vs[dn * 16 + lr][kk * 32 + lg * 8];
                o[dn] = __builtin_amdgcn_mfma_f32_16x16x32_bf16(pa, vb, o[dn], 0, 0, 0);
            }
        }
        __syncthreads();
    }

    #pragma unroll
    for (int dn = 0; dn < 4; ++dn)
        #pragma unroll
        for (int r = 0; r < 4; ++r) {
            int row = qr0 + 4 * lg + r;
            Og[(size_t)row * DM + hoff + dn * 16 + lr] = f2bf(o[dn][r] / lsum[r]);
        }
}

extern "C" void kernel_launch(void* const* d_in, const int* in_sizes, int n_in,
                              void* d_out, int out_size, void* d_ws, size_t ws_size,
                              hipStream_t stream) {
    const float* x     = (const float*)d_in[0];
    const float* ln1_g = (const float*)d_in[1];
    const float* ln1_b = (const float*)d_in[2];
    const float* Wq    = (const float*)d_in[3];
    const float* Wk    = (const float*)d_in[4];
    const float* Wv    = (const float*)d_in[5];
    const float* Wo    = (const float*)d_in[6];
    const float* bo    = (const float*)d_in[7];
    const float* ln2_g = (const float*)d_in[8];
    const float* ln2_b = (const float*)d_in[9];
    const float* Wfc   = (const float*)d_in[10];
    const float* bfc   = (const float*)d_in[11];
    const float* Wp    = (const float*)d_in[12];
    const float* bp    = (const float*)d_in[13];
    const float* lnf_g = (const float*)d_in[14];
    const float* lnf_b = (const float*)d_in[15];
    const float* Wlm   = (const float*)d_in[16];

    char* ws = (char*)d_ws;
    float*  h   = (float*)ws;   ws += (size_t)SEQ * DM * 4;
    ushort* hn  = (ushort*)ws;  ws += (size_t)SEQ * DM * 2;
    ushort* qb_ = (ushort*)ws;  ws += (size_t)SEQ * DM * 2;
    ushort* kb_ = (ushort*)ws;  ws += (size_t)SEQ * DM * 2;
    ushort* vb_ = (ushort*)ws;  ws += (size_t)SEQ * DM * 2;
    ushort* ab_ = (ushort*)ws;  ws += (size_t)SEQ * DM * 2;
    ushort* fb_ = (ushort*)ws;  ws += (size_t)SEQ * FF * 2;

    hipMemcpyAsync(h, x, (size_t)SEQ * DM * 4, hipMemcpyDeviceToDevice, stream);

    dim3 blk(256);
    dim3 gdd(SEQ / 64, DM / 64);
    dim3 gdf(SEQ / 64, FF / 64);
    dim3 gda(SEQ / 64, NH);
    dim3 gdl(SEQ / 64, (NV + 63) / 64);

    for (int l = 0; l < NL; ++l) {
        ln_kernel<<<SEQ, blk, 0, stream>>>(h, ln1_g + l * DM, ln1_b + l * DM, hn);
        gemm64<0><<<gdd, blk, 0, stream>>>(hn, Wq + (size_t)l * DM * DM, nullptr, nullptr, qb_, SEQ, DM, DM);
        gemm64<0><<<gdd, blk, 0, stream>>>(hn, Wk + (size_t)l * DM * DM, nullptr, nullptr, kb_, SEQ, DM, DM);
        gemm64<0><<<gdd, blk, 0, stream>>>(hn, Wv + (size_t)l * DM * DM, nullptr, nullptr, vb_, SEQ, DM, DM);
        attn_kernel<<<gda, blk, 0, stream>>>(qb_, kb_, vb_, ab_);
        gemm64<1><<<gdd, blk, 0, stream>>>(ab_, Wo + (size_t)l * DM * DM, bo + l * DM, h, h, SEQ, DM, DM);
        ln_kernel<<<SEQ, blk, 0, stream>>>(h, ln2_g + l * DM, ln2_b + l * DM, hn);
        gemm64<2><<<gdf, blk, 0, stream>>>(hn, Wfc + (size_t)l * DM * FF, bfc + l * FF, nullptr, fb_, SEQ, FF, DM);
        gemm64<1><<<gdd, blk, 0, stream>>>(fb_, Wp + (size_t)l * FF * DM, bp + l * DM, h, h, SEQ, DM, FF);
    }
    ln_kernel<<<SEQ, blk, 0, stream>>>(h, lnf_g, lnf_b, hn);
    gemm64<3><<<gdl, blk, 0, stream>>>(hn, Wlm, nullptr, nullptr, d_out, SEQ, NV, DM);
}

// Round 2
// 3230.796 us; speedup vs baseline: 2.1253x; 2.1253x over previous
//
#include <hip/hip_runtime.h>
#include <hip/hip_bf16.h>
#include <math.h>

typedef unsigned short ushort;
typedef __attribute__((ext_vector_type(8))) short short8;
typedef __attribute__((ext_vector_type(4))) float f4v;

constexpr int SEQ = 2048;
constexpr int DM  = 768;
constexpr int NH  = 12;
constexpr int HDM = 64;
constexpr int FF  = 3072;
constexpr int NL  = 12;
constexpr int NV  = 50257;
constexpr int NVP = 50304;   // NV padded to 128

__device__ inline ushort f2bf(float f) {
    union { float f; unsigned u; } v; v.f = f;
    unsigned r = v.u + 0x7fffu + ((v.u >> 16) & 1u);
    return (ushort)(r >> 16);
}

__device__ __forceinline__ void gld16(const ushort* g, ushort* l) {
    __builtin_amdgcn_global_load_lds(
        (const __attribute__((address_space(1))) void*)g,
        (__attribute__((address_space(3))) void*)l, 16, 0, 0);
}

// ---------------- LayerNorm: fp32 in -> bf16 out ----------------
__global__ __launch_bounds__(256) void ln_kernel(const float* __restrict__ x,
                                                 const float* __restrict__ g,
                                                 const float* __restrict__ b,
                                                 ushort* __restrict__ out) {
    int row = blockIdx.x;
    int t = threadIdx.x;
    const float* xr = x + (size_t)row * DM;
    float v0 = xr[t], v1 = xr[t + 256], v2 = xr[t + 512];
    float s = v0 + v1 + v2;
    float s2 = v0 * v0 + v1 * v1 + v2 * v2;
    for (int m = 1; m < 64; m <<= 1) { s += __shfl_xor(s, m); s2 += __shfl_xor(s2, m); }
    __shared__ float ls[4], ls2[4];
    int w = t >> 6;
    if ((t & 63) == 0) { ls[w] = s; ls2[w] = s2; }
    __syncthreads();
    s = ls[0] + ls[1] + ls[2] + ls[3];
    s2 = ls2[0] + ls2[1] + ls2[2] + ls2[3];
    float mu = s * (1.0f / DM);
    float var = s2 * (1.0f / DM) - mu * mu;
    float rs = rsqrtf(var + 1e-5f);
    ushort* o = out + (size_t)row * DM;
    o[t]       = f2bf((v0 - mu) * rs * g[t]       + b[t]);
    o[t + 256] = f2bf((v1 - mu) * rs * g[t + 256] + b[t + 256]);
    o[t + 512] = f2bf((v2 - mu) * rs * g[t + 512] + b[t + 512]);
}

// ---------------- transpose-convert: in fp32 [K][N] -> out bf16 [N][K] -----
__global__ __launch_bounds__(256) void cvt_t(const float* __restrict__ in, size_t inL,
                                             ushort* __restrict__ out, size_t outL,
                                             int K, int N) {
    __shared__ ushort T[64][72];
    int l = blockIdx.z;
    const float* ip = in + (size_t)l * inL;
    ushort* op = out + (size_t)l * outL;
    int kb = blockIdx.x * 64, nb = blockIdx.y * 64;
    int t = threadIdx.x;
    int nl = t & 63, ks = (t >> 6) * 16;
    int n = nb + nl;
    #pragma unroll
    for (int j = 0; j < 16; ++j) {
        float f = (n < N) ? ip[(size_t)(kb + ks + j) * N + n] : 0.f;
        T[nl][ks + j] = f2bf(f);
    }
    __syncthreads();
    int r = t >> 2, c4 = (t & 3) * 16;
    *(short8*)(op + (size_t)(nb + r) * K + kb + c4)     = *(const short8*)&T[r][c4];
    *(short8*)(op + (size_t)(nb + r) * K + kb + c4 + 8) = *(const short8*)&T[r][c4 + 8];
}

// ---------------- GEMM: C[M,N] = A_bf16[M,K] @ Bt_bf16[N,K]^T (+epilogue) --
// m97 structure: BK=64, global_load_lds(16B), XOR bank swizzle via
// pre-swizzled global source (linear LDS dest) + swizzled ds_read.
// EPI 0: bf16 out          EPI 1: fp32 out = acc + bias[col] + res
// EPI 2: bf16 gelu(acc+b)  EPI 3: fp32 out = acc, col<N guarded
template <int BM, int BN, int EPI>
__global__ __launch_bounds__(256) void gemmT(const ushort* __restrict__ A,
                                             const ushort* __restrict__ Bt,
                                             const float* __restrict__ bias,
                                             const float* __restrict__ res,
                                             void* __restrict__ outp,
                                             int M, int N, int K, int ldOut) {
    constexpr int FM = BM / 32;
    constexpr int FN = BN / 32;
    __shared__ ushort As[BM * 64];
    __shared__ ushort Bs[BN * 64];
    int tid = threadIdx.x, lane = tid & 63, wave = tid >> 6;
    int wm = (wave >> 1) * (BM / 2), wn = (wave & 1) * (BN / 2);
    int mBase = blockIdx.x * BM, nBase = blockIdx.y * BN;
    int lr = lane & 15, lg = lane >> 4;
    int swz = (lr & 7) << 3;   // element-offset XOR for swizzled reads

    f4v acc[FM][FN];
    #pragma unroll
    for (int i = 0; i < FM; ++i)
        #pragma unroll
        for (int j = 0; j < FN; ++j) acc[i][j] = (f4v){0.f, 0.f, 0.f, 0.f};

    int cBase = wave * 64 + lane;

    for (int kb = 0; kb < K; kb += 64) {
        #pragma unroll
        for (int i = 0; i < BM / 32; ++i) {
            int c = i * 256 + cBase;
            int row = c >> 3;
            int kc = (c & 7) ^ (row & 7);     // inverse-swizzled source
            gld16(A + (size_t)(mBase + row) * K + kb + kc * 8,
                  As + (size_t)(i * 256 + wave * 64) * 8);
        }
        #pragma unroll
        for (int i = 0; i < BN / 32; ++i) {
            int c = i * 256 + cBase;
            int row = c >> 3;
            int kc = (c & 7) ^ (row & 7);
            gld16(Bt + (size_t)(nBase + row) * K + kb + kc * 8,
                  Bs + (size_t)(i * 256 + wave * 64) * 8);
        }
        __syncthreads();
        #pragma unroll
        for (int kk = 0; kk < 2; ++kk) {
            short8 a[FM], b[FN];
            #pragma unroll
            for (int fr = 0; fr < FM; ++fr)
                a[fr] = *(const short8*)(As + (wm + fr * 16 + lr) * 64 + ((((kk * 4 + lg) << 3)) ^ swz));
            #pragma unroll
            for (int fc = 0; fc < FN; ++fc)
                b[fc] = *(const short8*)(Bs + (wn + fc * 16 + lr) * 64 + ((((kk * 4 + lg) << 3)) ^ swz));
            #pragma unroll
            for (int fr = 0; fr < FM; ++fr)
                #pragma unroll
                for (int fc = 0; fc < FN; ++fc)
                    acc[fr][fc] = __builtin_amdgcn_mfma_f32_16x16x32_bf16(a[fr], b[fc], acc[fr][fc], 0, 0, 0);
        }
        __syncthreads();
    }

    #pragma unroll
    for (int fr = 0; fr < FM; ++fr)
        #pragma unroll
        for (int fc = 0; fc < FN; ++fc)
            #pragma unroll
            for (int r = 0; r < 4; ++r) {
                int row = mBase + wm + fr * 16 + 4 * lg + r;
                int col = nBase + wn + fc * 16 + lr;
                float v = acc[fr][fc][r];
                if constexpr (EPI == 0) {
                    ((ushort*)outp)[(size_t)row * ldOut + col] = f2bf(v);
                } else if constexpr (EPI == 1) {
                    v += bias[col] + res[(size_t)row * ldOut + col];
                    ((float*)outp)[(size_t)row * ldOut + col] = v;
                } else if constexpr (EPI == 2) {
                    v += bias[col];
                    v = 0.5f * v * (1.f + erff(v * 0.70710678118f));
                    ((ushort*)outp)[(size_t)row * ldOut + col] = f2bf(v);
                } else {
                    if (col < N) ((float*)outp)[(size_t)row * ldOut + col] = v;
                }
            }
}

// ---------------- old fp32-B GEMM (fallback path only) ---------------------
template <int EPI>
__global__ __launch_bounds__(256) void gemm64(const ushort* __restrict__ A,
                                              const float* __restrict__ B,
                                              const float* __restrict__ bias,
                                              const float* __restrict__ res,
                                              void* __restrict__ outp,
                                              int M, int N, int K) {
    __shared__ ushort As[64][64];
    __shared__ ushort Bs[64][72];
    int tid = threadIdx.x;
    int lane = tid & 63, wave = tid >> 6;
    int wm = (wave >> 1) * 32, wn = (wave & 1) * 32;
    int mBase = blockIdx.x * 64, nBase = blockIdx.y * 64;
    int lr = lane & 15, lg = lane >> 4;

    const f4v fz = {0.f, 0.f, 0.f, 0.f};
    f4v acc[2][2];
    acc[0][0] = fz; acc[0][1] = fz; acc[1][0] = fz; acc[1][1] = fz;

    int ar = tid >> 2, ac = (tid & 3) * 16;
    int br = tid >> 2, bc = (tid & 3) * 16;

    for (int kb = 0; kb < K; kb += 64) {
        const short8* ag = (const short8*)(A + (size_t)(mBase + ar) * K + kb + ac);
        *(short8*)&As[ar][ac]     = ag[0];
        *(short8*)&As[ar][ac + 8] = ag[1];
        if constexpr (EPI == 3) {
            #pragma unroll
            for (int j = 0; j < 16; ++j) {
                int col = nBase + bc + j;
                float f = (col < N) ? B[(size_t)(kb + br) * N + col] : 0.f;
                Bs[bc + j][br] = f2bf(f);
            }
        } else {
            const float4* bg = (const float4*)(B + (size_t)(kb + br) * N + nBase + bc);
            float fv[16];
            *(float4*)&fv[0]  = bg[0];
            *(float4*)&fv[4]  = bg[1];
            *(float4*)&fv[8]  = bg[2];
            *(float4*)&fv[12] = bg[3];
            #pragma unroll
            for (int j = 0; j < 16; ++j) Bs[bc + j][br] = f2bf(fv[j]);
        }
        __syncthreads();
        #pragma unroll
        for (int kk = 0; kk < 2; ++kk) {
            short8 a0 = *(const short8*)&As[wm + lr][kk * 32 + lg * 8];
            short8 a1 = *(const short8*)&As[wm + 16 + lr][kk * 32 + lg * 8];
            short8 b0 = *(const short8*)&Bs[wn + lr][kk * 32 + lg * 8];
            short8 b1 = *(const short8*)&Bs[wn + 16 + lr][kk * 32 + lg * 8];
            acc[0][0] = __builtin_amdgcn_mfma_f32_16x16x32_bf16(a0, b0, acc[0][0], 0, 0, 0);
            acc[0][1] = __builtin_amdgcn_mfma_f32_16x16x32_bf16(a0, b1, acc[0][1], 0, 0, 0);
            acc[1][0] = __builtin_amdgcn_mfma_f32_16x16x32_bf16(a1, b0, acc[1][0], 0, 0, 0);
            acc[1][1] = __builtin_amdgcn_mfma_f32_16x16x32_bf16(a1, b1, acc[1][1], 0, 0, 0);
        }
        __syncthreads();
    }

    #pragma unroll
    for (int fm = 0; fm < 2; ++fm)
        #pragma unroll
        for (int fn = 0; fn < 2; ++fn)
            #pragma unroll
            for (int r = 0; r < 4; ++r) {
                int row = mBase + wm + fm * 16 + 4 * lg + r;
                int col = nBase + wn + fn * 16 + lr;
                float v = acc[fm][fn][r];
                if constexpr (EPI == 0) {
                    ((ushort*)outp)[(size_t)row * N + col] = f2bf(v);
                } else if constexpr (EPI == 1) {
                    v += bias[col] + res[(size_t)row * N + col];
                    ((float*)outp)[(size_t)row * N + col] = v;
                } else if constexpr (EPI == 2) {
                    v += bias[col];
                    v = 0.5f * v * (1.f + erff(v * 0.70710678118f));
                    ((ushort*)outp)[(size_t)row * N + col] = f2bf(v);
                } else {
                    if (col < N) ((float*)outp)[(size_t)row * N + col] = v;
                }
            }
}

// ---------------- Flash attention (causal, no 1/sqrt(d) scale) -------------
// Q/K/V read with row stride ld (supports packed QKV buffer); O stride DM.
__global__ __launch_bounds__(256) void attn_kernel(const ushort* __restrict__ Qg,
                                                   const ushort* __restrict__ Kg,
                                                   const ushort* __restrict__ Vg,
                                                   ushort* __restrict__ Og,
                                                   int ld) {
    __shared__ ushort Ks[64][64];
    __shared__ ushort Vs[64][72];
    __shared__ ushort Ps[4][16][64];
    int tid = threadIdx.x, lane = tid & 63, wave = tid >> 6;
    int qb = blockIdx.x, head = blockIdx.y;
    int lr = lane & 15, lg = lane >> 4;
    int qr0 = qb * 64 + wave * 16;
    size_t hoff = (size_t)head * HDM;

    short8 qf0 = *(const short8*)(Qg + (size_t)(qr0 + lr) * ld + hoff + lg * 8);
    short8 qf1 = *(const short8*)(Qg + (size_t)(qr0 + lr) * ld + hoff + 32 + lg * 8);

    const f4v fz = {0.f, 0.f, 0.f, 0.f};
    f4v o[4];
    o[0] = fz; o[1] = fz; o[2] = fz; o[3] = fz;
    float mrow[4] = {-1e30f, -1e30f, -1e30f, -1e30f};
    float lsum[4] = {0.f, 0.f, 0.f, 0.f};

    int r_ = tid >> 2, c_ = (tid & 3) * 16;

    for (int kb = 0; kb <= qb; ++kb) {
        const short8* kg = (const short8*)(Kg + (size_t)(kb * 64 + r_) * ld + hoff + c_);
        *(short8*)&Ks[r_][c_]     = kg[0];
        *(short8*)&Ks[r_][c_ + 8] = kg[1];
        const short8* vg = (const short8*)(Vg + (size_t)(kb * 64 + r_) * ld + hoff + c_);
        short8 v0 = vg[0], v1 = vg[1];
        #pragma unroll
        for (int j = 0; j < 8; ++j) {
            Vs[c_ + j][r_]     = (ushort)v0[j];
            Vs[c_ + 8 + j][r_] = (ushort)v1[j];
        }
        __syncthreads();

        f4v s[4];
        #pragma unroll
        for (int n = 0; n < 4; ++n) {
            short8 k0 = *(const short8*)&Ks[n * 16 + lr][lg * 8];
            short8 k1 = *(const short8*)&Ks[n * 16 + lr][32 + lg * 8];
            f4v z = fz;
            z = __builtin_amdgcn_mfma_f32_16x16x32_bf16(qf0, k0, z, 0, 0, 0);
            s[n] = __builtin_amdgcn_mfma_f32_16x16x32_bf16(qf1, k1, z, 0, 0, 0);
        }
        if (kb == qb) {
            #pragma unroll
            for (int n = 0; n < 4; ++n)
                #pragma unroll
                for (int r = 0; r < 4; ++r) {
                    int col = kb * 64 + n * 16 + lr;
                    int row = qr0 + 4 * lg + r;
                    if (col > row) s[n][r] = -1e38f;
                }
        }

        #pragma unroll
        for (int r = 0; r < 4; ++r) {
            float mx = fmaxf(fmaxf(s[0][r], s[1][r]), fmaxf(s[2][r], s[3][r]));
            mx = fmaxf(mx, __shfl_xor(mx, 1));
            mx = fmaxf(mx, __shfl_xor(mx, 2));
            mx = fmaxf(mx, __shfl_xor(mx, 4));
            mx = fmaxf(mx, __shfl_xor(mx, 8));
            float mnew = fmaxf(mrow[r], mx);
            float corr = expf(mrow[r] - mnew);
            float ps0 = expf(s[0][r] - mnew);
            float ps1 = expf(s[1][r] - mnew);
            float ps2 = expf(s[2][r] - mnew);
            float ps3 = expf(s[3][r] - mnew);
            float rs = ps0 + ps1 + ps2 + ps3;
            rs += __shfl_xor(rs, 1);
            rs += __shfl_xor(rs, 2);
            rs += __shfl_xor(rs, 4);
            rs += __shfl_xor(rs, 8);
            lsum[r] = lsum[r] * corr + rs;
            mrow[r] = mnew;
            o[0][r] *= corr; o[1][r] *= corr; o[2][r] *= corr; o[3][r] *= corr;
            Ps[wave][4 * lg + r][0 * 16 + lr] = f2bf(ps0);
            Ps[wave][4 * lg + r][1 * 16 + lr] = f2bf(ps1);
            Ps[wave][4 * lg + r][2 * 16 + lr] = f2bf(ps2);
            Ps[wave][4 * lg + r][3 * 16 + lr] = f2bf(ps3);
        }
        __syncthreads();

        #pragma unroll
        for (int kk = 0; kk < 2; ++kk) {
            short8 pa = *(const short8*)&Ps[wave][lr][kk * 32 + lg * 8];
            #pragma unroll
            for (int dn = 0; dn < 4; ++dn) {
                short8 vb = *(const short8*)&Vs[dn * 16 + lr][kk * 32 + lg * 8];
                o[dn] = __builtin_amdgcn_mfma_f32_16x16x32_bf16(pa, vb, o[dn], 0, 0, 0);
            }
        }
        __syncthreads();
    }

    #pragma unroll
    for (int dn = 0; dn < 4; ++dn)
        #pragma unroll
        for (int r = 0; r < 4; ++r) {
            int row = qr0 + 4 * lg + r;
            Og[(size_t)row * DM + hoff + dn * 16 + lr] = f2bf(o[dn][r] / lsum[r]);
        }
}

extern "C" void kernel_launch(void* const* d_in, const int* in_sizes, int n_in,
                              void* d_out, int out_size, void* d_ws, size_t ws_size,
                              hipStream_t stream) {
    const float* x     = (const float*)d_in[0];
    const float* ln1_g = (const float*)d_in[1];
    const float* ln1_b = (const float*)d_in[2];
    const float* Wq    = (const float*)d_in[3];
    const float* Wk    = (const float*)d_in[4];
    const float* Wv    = (const float*)d_in[5];
    const float* Wo    = (const float*)d_in[6];
    const float* bo    = (const float*)d_in[7];
    const float* ln2_g = (const float*)d_in[8];
    const float* ln2_b = (const float*)d_in[9];
    const float* Wfc   = (const float*)d_in[10];
    const float* bfc   = (const float*)d_in[11];
    const float* Wp    = (const float*)d_in[12];
    const float* bp    = (const float*)d_in[13];
    const float* lnf_g = (const float*)d_in[14];
    const float* lnf_b = (const float*)d_in[15];
    const float* Wlm   = (const float*)d_in[16];

    dim3 blk(256);

    // ---- workspace layout (new path) ----
    size_t offs[11];
    size_t need = 0;
    size_t sizes[10] = {
        (size_t)SEQ * DM * 4,          // h (fp32)
        (size_t)SEQ * DM * 2,          // hn
        (size_t)SEQ * 2304 * 2,        // qkv packed
        (size_t)SEQ * DM * 2,          // ab
        (size_t)SEQ * FF * 2,          // fb
        (size_t)NL * 2304 * DM * 2,    // qkvw^T packed
        (size_t)NL * DM * DM * 2,      // Wo^T
        (size_t)NL * FF * DM * 2,      // Wfc^T [3072][768]
        (size_t)NL * DM * FF * 2,      // Wp^T  [768][3072]
        (size_t)NVP * DM * 2,          // Wlm^T [50304][768]
    };
    for (int i = 0; i < 10; ++i) { offs[i] = need; need += sizes[i]; }
    offs[10] = need;

    if (ws_size >= need) {
        char* ws = (char*)d_ws;
        float*  h    = (float*)(ws + offs[0]);
        ushort* hn   = (ushort*)(ws + offs[1]);
        ushort* qkv  = (ushort*)(ws + offs[2]);
        ushort* ab_  = (ushort*)(ws + offs[3]);
        ushort* fb_  = (ushort*)(ws + offs[4]);
        ushort* qkvw = (ushort*)(ws + offs[5]);
        ushort* wow  = (ushort*)(ws + offs[6]);
        ushort* fcw  = (ushort*)(ws + offs[7]);
        ushort* wpw  = (ushort*)(ws + offs[8]);
        ushort* lmw  = (ushort*)(ws + offs[9]);

        hipMemcpyAsync(h, x, (size_t)SEQ * DM * 4, hipMemcpyDeviceToDevice, stream);

        // weight conversions (once per launch)
        cvt_t<<<dim3(12, 12, NL), blk, 0, stream>>>(Wq, (size_t)DM * DM, qkvw,            (size_t)2304 * DM, DM, DM);
        cvt_t<<<dim3(12, 12, NL), blk, 0, stream>>>(Wk, (size_t)DM * DM, qkvw + DM * DM,  (size_t)2304 * DM, DM, DM);
        cvt_t<<<dim3(12, 12, NL), blk, 0, stream>>>(Wv, (size_t)DM * DM, qkvw + 2 * DM * DM, (size_t)2304 * DM, DM, DM);
        cvt_t<<<dim3(12, 12, NL), blk, 0, stream>>>(Wo, (size_t)DM * DM, wow, (size_t)DM * DM, DM, DM);
        cvt_t<<<dim3(12, 48, NL), blk, 0, stream>>>(Wfc, (size_t)DM * FF, fcw, (size_t)FF * DM, DM, FF);
        cvt_t<<<dim3(48, 12, NL), blk, 0, stream>>>(Wp,  (size_t)FF * DM, wpw, (size_t)DM * FF, FF, DM);
        cvt_t<<<dim3(12, 786, 1), blk, 0, stream>>>(Wlm, 0, lmw, 0, DM, NV);

        for (int l = 0; l < NL; ++l) {
            const ushort* qw = qkvw + (size_t)l * 2304 * DM;
            ln_kernel<<<SEQ, blk, 0, stream>>>(h, ln1_g + l * DM, ln1_b + l * DM, hn);
            gemmT<128, 128, 0><<<dim3(16, 18), blk, 0, stream>>>(hn, qw, nullptr, nullptr, qkv, SEQ, 2304, DM, 2304);
            attn_kernel<<<dim3(SEQ / 64, NH), blk, 0, stream>>>(qkv, qkv + 768, qkv + 1536, ab_, 2304);
            gemmT<128, 64, 1><<<dim3(16, 12), blk, 0, stream>>>(ab_, wow + (size_t)l * DM * DM, bo + l * DM, h, h, SEQ, DM, DM, DM);
            ln_kernel<<<SEQ, blk, 0, stream>>>(h, ln2_g + l * DM, ln2_b + l * DM, hn);
            gemmT<128, 128, 2><<<dim3(16, 24), blk, 0, stream>>>(hn, fcw + (size_t)l * FF * DM, bfc + l * FF, nullptr, fb_, SEQ, FF, DM, FF);
            gemmT<128, 64, 1><<<dim3(16, 12), blk, 0, stream>>>(fb_, wpw + (size_t)l * DM * FF, bp + l * DM, h, h, SEQ, DM, FF, DM);
        }
        ln_kernel<<<SEQ, blk, 0, stream>>>(h, lnf_g, lnf_b, hn);
        gemmT<128, 128, 3><<<dim3(16, NVP / 128), blk, 0, stream>>>(hn, lmw, nullptr, nullptr, d_out, SEQ, NV, DM, NV);
        return;
    }

    // ---------------- fallback: round-1 path (fp32-B GEMMs) ----------------
    char* ws = (char*)d_ws;
    float*  h   = (float*)ws;   ws += (size_t)SEQ * DM * 4;
    ushort* hn  = (ushort*)ws;  ws += (size_t)SEQ * DM * 2;
    ushort* qb_ = (ushort*)ws;  ws += (size_t)SEQ * DM * 2;
    ushort* kb_ = (ushort*)ws;  ws += (size_t)SEQ * DM * 2;
    ushort* vb_ = (ushort*)ws;  ws += (size_t)SEQ * DM * 2;
    ushort* ab_ = (ushort*)ws;  ws += (size_t)SEQ * DM * 2;
    ushort* fb_ = (ushort*)ws;  ws += (size_t)SEQ * FF * 2;

    hipMemcpyAsync(h, x, (size_t)SEQ * DM * 4, hipMemcpyDeviceToDevice, stream);

    dim3 gdd(SEQ / 64, DM / 64);
    dim3 gdf(SEQ / 64, FF / 64);
    dim3 gda(SEQ / 64, NH);
    dim3 gdl(SEQ / 64, (NV + 63) / 64);

    for (int l = 0; l < NL; ++l) {
        ln_kernel<<<SEQ, blk, 0, stream>>>(h, ln1_g + l * DM, ln1_b + l * DM, hn);
        gemm64<0><<<gdd, blk, 0, stream>>>(hn, Wq + (size_t)l * DM * DM, nullptr, nullptr, qb_, SEQ, DM, DM);
        gemm64<0><<<gdd, blk, 0, stream>>>(hn, Wk + (size_t)l * DM * DM, nullptr, nullptr, kb_, SEQ, DM, DM);
        gemm64<0><<<gdd, blk, 0, stream>>>(hn, Wv + (size_t)l * DM * DM, nullptr, nullptr, vb_, SEQ, DM, DM);
        attn_kernel<<<gda, blk, 0, stream>>>(qb_, kb_, vb_, ab_, DM);
        gemm64<1><<<gdd, blk, 0, stream>>>(ab_, Wo + (size_t)l * DM * DM, bo + l * DM, h, h, SEQ, DM, DM);
        ln_kernel<<<SEQ, blk, 0, stream>>>(h, ln2_g + l * DM, ln2_b + l * DM, hn);
        gemm64<2><<<gdf, blk, 0, stream>>>(hn, Wfc + (size_t)l * DM * FF, bfc + l * FF, nullptr, fb_, SEQ, FF, DM);
        gemm64<1><<<gdd, blk, 0, stream>>>(fb_, Wp + (size_t)l * FF * DM, bp + l * DM, h, h, SEQ, DM, FF);
    }
    ln_kernel<<<SEQ, blk, 0, stream>>>(h, lnf_g, lnf_b, hn);
    gemm64<3><<<gdl, blk, 0, stream>>>(hn, Wlm, nullptr, nullptr, d_out, SEQ, NV, DM);
}